// Round 2
// baseline (421.467 us; speedup 1.0000x reference)
//
#include <hip/hip_runtime.h>

// x[2,8,540,960] f32, filt[16,8] f32, scale=3 (runtime), out[2,8,1620,2880] f32.
#define Hh 540
#define Ww 960
#define OHh 1620
#define OWw 2880
#define OW4 720                   // OWw / 4
#define PERC (OHh * OW4)          // float4s per (b,c) image = 1,166,400

__global__ __launch_bounds__(256) void vtm_upsample(
    const float* __restrict__ x,
    const float* __restrict__ filt,
    const int* __restrict__ scale_p,
    float* __restrict__ out)
{
    __shared__ float s_f[16][8];
    __shared__ float s_sum[16];
    __shared__ unsigned short rtab[OHh];  // r0(10b) | fy(4b)<<10 | sat<<14
    __shared__ uint2 ctab[OW4];           // 4x 15-bit entries: c0(10b)|fx(4b)<<10|sat<<14

    const int tid = threadIdx.x;
    const unsigned scale = (unsigned)*scale_p;

    if (tid < 128) ((float*)s_f)[tid] = filt[tid];
    __syncthreads();
    if (tid < 16) {
        float s = 0.f;
        #pragma unroll
        for (int k = 0; k < 8; ++k) s += s_f[tid][k];
        s_sum[tid] = s;
    }
    // Row table: replicates ref=int(oy*16384/scale); integer=ref>>4; frac=ref&15.
    for (int i = tid; i < OHh; i += 256) {
        const unsigned ref = ((unsigned)i * 16384u) / scale;
        const int ii = (int)(ref >> 4);
        const unsigned f = ref & 15u;
        const int lo = min(max(ii - 3, 0), Hh - 1);
        const int hi = min(max(ii + 4, 0), Hh - 1);
        rtab[i] = (unsigned short)((unsigned)lo | (f << 10) | ((lo == hi) ? 0x4000u : 0u));
    }
    // Column table, packed per output-float4.
    for (int g = tid; g < OW4; g += 256) {
        unsigned e[4];
        #pragma unroll
        for (int u = 0; u < 4; ++u) {
            const unsigned ox = (unsigned)(4 * g + u);
            const unsigned ref = (ox * 16384u) / scale;
            const int ii = (int)(ref >> 4);
            const unsigned f = ref & 15u;
            const int lo = min(max(ii - 3, 0), Ww - 1);
            const int hi = min(max(ii + 4, 0), Ww - 1);
            e[u] = (unsigned)lo | (f << 10) | ((lo == hi) ? 0x4000u : 0u);
        }
        ctab[g] = make_uint2(e[0] | (e[1] << 15), e[2] | (e[3] << 15));
    }
    __syncthreads();

    const unsigned bc = blockIdx.y;
    const float* __restrict__ xp = x + (size_t)bc * (Hh * Ww);
    float* __restrict__ op = out + (size_t)bc * ((size_t)OHh * OWw);
    const float inv = 1.0f / 4096.0f;
    const unsigned stride = gridDim.x * 256u;

    for (unsigned v = blockIdx.x * 256u + (unsigned)tid; v < PERC; v += stride) {
        const unsigned g  = v % OW4;
        const unsigned oy = v / OW4;
        const unsigned rinfo = rtab[oy];
        const uint2 ci = ctab[g];
        const unsigned e0 = ci.x & 0x7FFFu, e1 = ci.x >> 15;
        const unsigned e2 = ci.y & 0x7FFFu, e3 = ci.y >> 15;
        const int r0 = (int)(rinfo & 1023u);
        const float Sh = s_sum[(rinfo >> 10) & 15u];
        float vals[4];

        if (rinfo & e0 & e1 & e2 & e3 & 0x4000u) {
            // All 4 columns + row fully clamp-collapsed: 8-tap x 8-tap folds to
            // x[r0][c0] * sum(coef_x) * sum(coef_y).
            const float c = Sh * inv;
            const float* __restrict__ rp = xp + r0 * Ww;
            vals[0] = rp[e0 & 1023u] * s_sum[(e0 >> 10) & 15u] * c;
            vals[1] = rp[e1 & 1023u] * s_sum[(e1 >> 10) & 15u] * c;
            vals[2] = rp[e2 & 1023u] * s_sum[(e2 >> 10) & 15u] * c;
            vals[3] = rp[e3 & 1023u] * s_sum[(e3 >> 10) & 15u] * c;
        } else {
            // Rare path (oy<2 or ox<3 for scale=3): full 8x8 MAC, recompute phases.
            const unsigned refy = ((unsigned)oy * 16384u) / scale;
            const int iy = (int)(refy >> 4);
            const int fy = (int)(refy & 15u);
            const bool rsat = (rinfo & 0x4000u) != 0;
            const unsigned ee[4] = {e0, e1, e2, e3};
            #pragma unroll
            for (int u = 0; u < 4; ++u) {
                const unsigned e = ee[u];
                if ((e & 0x4000u) && rsat) {
                    vals[u] = xp[r0 * Ww + (int)(e & 1023u)] * s_sum[(e >> 10) & 15u] * Sh * inv;
                } else {
                    const unsigned ox = g * 4u + (unsigned)u;
                    const unsigned refx = (ox * 16384u) / scale;
                    const int ix = (int)(refx >> 4);
                    const int fx = (int)(refx & 15u);
                    float acc = 0.f;
                    #pragma unroll
                    for (int j = 0; j < 8; ++j) {
                        const int ry = min(max(iy + j - 3, 0), Hh - 1);
                        const float* __restrict__ rp2 = xp + ry * Ww;
                        float h = 0.f;
                        #pragma unroll
                        for (int k = 0; k < 8; ++k) {
                            const int cx = min(max(ix + k - 3, 0), Ww - 1);
                            h = fmaf(s_f[fx][k], rp2[cx], h);
                        }
                        acc = fmaf(s_f[fy][j], h, acc);
                    }
                    vals[u] = acc * inv;
                }
            }
        }
        *reinterpret_cast<float4*>(op + (size_t)oy * OWw + g * 4u) =
            make_float4(vals[0], vals[1], vals[2], vals[3]);
    }
}

extern "C" void kernel_launch(void* const* d_in, const int* in_sizes, int n_in,
                              void* d_out, int out_size, void* d_ws, size_t ws_size,
                              hipStream_t stream) {
    const float* x       = (const float*)d_in[0];
    const float* filt    = (const float*)d_in[1];
    const int*   scale_p = (const int*)d_in[2];
    float* out = (float*)d_out;
    dim3 grid(128, 16), block(256);
    vtm_upsample<<<grid, block, 0, stream>>>(x, filt, scale_p, out);
}

// Round 4
// 382.718 us; speedup vs baseline: 1.1012x; 1.1012x over previous
//
#include <hip/hip_runtime.h>

// x[2,8,540,960] f32, filt[16,8] f32, scale=3 (runtime), out[2,8,1620,2880] f32.
#define Hh 540
#define Ww 960
#define OHh 1620
#define OWw 2880
#define OW4 720   // float4 groups per output row

typedef float floatx4 __attribute__((ext_vector_type(4)));  // clang-native for nontemporal builtin

// One block per (output row oy, image bc). 256 threads cover 720 float4 groups
// in 3 grid-stride steps. Row phase is block-uniform; column phases computed
// per-thread (4 u32 divisions) — no LDS tables, no div/mod for position.
__global__ __launch_bounds__(256) void vtm_upsample(
    const float* __restrict__ x,
    const float* __restrict__ filt,
    const int* __restrict__ scale_p,
    float* __restrict__ out)
{
    __shared__ float s_f[16][8];
    __shared__ float s_sum[16];
    const int tid = threadIdx.x;
    if (tid < 128) ((float*)s_f)[tid] = filt[tid];
    __syncthreads();
    if (tid < 16) {
        float s = 0.f;
        #pragma unroll
        for (int k = 0; k < 8; ++k) s += s_f[tid][k];
        s_sum[tid] = s;
    }
    __syncthreads();

    const unsigned scale = (unsigned)*scale_p;
    const unsigned oy = blockIdx.x;
    const unsigned bc = blockIdx.y;
    const float inv = 1.0f / 4096.0f;

    const float* __restrict__ xp = x + (size_t)bc * (Hh * Ww);
    float* __restrict__ op = out + (size_t)bc * ((size_t)OHh * OWw) + (size_t)oy * OWw;

    // Row phase: replicates ref=int(oy*16384/scale); integer=ref>>4; frac=ref&15.
    const unsigned refy = (oy * 16384u) / scale;
    const int iy = (int)(refy >> 4);
    const int fy = (int)(refy & 15u);
    const int r0 = min(max(iy - 3, 0), Hh - 1);
    const int r7 = min(max(iy + 4, 0), Hh - 1);
    const bool rsat = (r0 == r7);          // block-uniform branch
    const float Shi = s_sum[fy] * inv;

    for (unsigned g = (unsigned)tid; g < OW4; g += 256u) {
        float vals[4];
        int cc[4], ff[4];
        bool cs[4];
        #pragma unroll
        for (int u = 0; u < 4; ++u) {
            const unsigned ox = 4u * g + (unsigned)u;
            const unsigned refx = (ox * 16384u) / scale;
            const int ix = (int)(refx >> 4);
            ff[u] = (int)(refx & 15u);
            const int c0 = min(max(ix - 3, 0), Ww - 1);
            const int c7 = min(max(ix + 4, 0), Ww - 1);
            cc[u] = c0;
            cs[u] = (c0 == c7);            // all 8 horizontal taps clamp to same col
        }

        if (rsat) {
            // Vertical 8-tap collapses to sum(coef_y) = s_sum[fy] on row r0.
            const float* __restrict__ rp = xp + r0 * Ww;
            #pragma unroll
            for (int u = 0; u < 4; ++u) {
                if (cs[u]) {
                    // Horizontal also collapses: single broadcast load.
                    vals[u] = rp[cc[u]] * s_sum[ff[u]] * Shi;
                } else {
                    // Rare (ox<3): horizontal 8-tap MAC on the single row.
                    const unsigned ox = 4u * g + (unsigned)u;
                    const int ix = (int)(((ox * 16384u) / scale) >> 4);
                    float h = 0.f;
                    #pragma unroll
                    for (int k = 0; k < 8; ++k) {
                        const int cx = min(max(ix + k - 3, 0), Ww - 1);
                        h = fmaf(s_f[ff[u]][k], rp[cx], h);
                    }
                    vals[u] = h * Shi;
                }
            }
        } else {
            // Rare (oy<2): full 8x8 MAC.
            #pragma unroll
            for (int u = 0; u < 4; ++u) {
                const unsigned ox = 4u * g + (unsigned)u;
                const int ix = (int)(((ox * 16384u) / scale) >> 4);
                float acc = 0.f;
                #pragma unroll
                for (int j = 0; j < 8; ++j) {
                    const int ry = min(max(iy + j - 3, 0), Hh - 1);
                    const float* __restrict__ rp2 = xp + ry * Ww;
                    float h = 0.f;
                    #pragma unroll
                    for (int k = 0; k < 8; ++k) {
                        const int cx = min(max(ix + k - 3, 0), Ww - 1);
                        h = fmaf(s_f[ff[u]][k], rp2[cx], h);
                    }
                    acc = fmaf(s_f[fy][j], h, acc);
                }
                vals[u] = acc * inv;
            }
        }

        floatx4 r4 = { vals[0], vals[1], vals[2], vals[3] };
        __builtin_nontemporal_store(r4, reinterpret_cast<floatx4*>(op + 4u * g));
    }
}

extern "C" void kernel_launch(void* const* d_in, const int* in_sizes, int n_in,
                              void* d_out, int out_size, void* d_ws, size_t ws_size,
                              hipStream_t stream) {
    const float* x       = (const float*)d_in[0];
    const float* filt    = (const float*)d_in[1];
    const int*   scale_p = (const int*)d_in[2];
    float* out = (float*)d_out;
    dim3 grid(OHh, 16), block(256);
    vtm_upsample<<<grid, block, 0, stream>>>(x, filt, scale_p, out);
}